// Round 19
// baseline (2385.084 us; speedup 1.0000x reference)
//
#include <hip/hip_runtime.h>
#include <stdint.h>

typedef float f32x4 __attribute__((ext_vector_type(4)));
typedef short s16x8 __attribute__((ext_vector_type(8)));
typedef unsigned u32x2 __attribute__((ext_vector_type(2)));

#define B_SZ 256
#define A_RG 196
#define DVD  2048
#define RNN  1024
#define H_SZ 512
#define M_TOT (B_SZ * A_RG)   // 50176 flat rows
#define BM 128
#define NKT  (DVD / 32)       // 64 K-tiles
#define NBLK (M_TOT / BM)     // 392

__device__ __forceinline__ unsigned short f2bf(float f) {
    unsigned u = __builtin_bit_cast(unsigned, f);
    u = u + 0x7FFFu + ((u >> 16) & 1u);   // RNE
    return (unsigned short)(u >> 16);
}

__device__ __forceinline__ unsigned cvt2(float a, float b) {
    unsigned r;
    asm("v_cvt_pk_bf16_f32 %0, %1, %2" : "=v"(r) : "v"(a), "v"(b));
    return r;
}

// ---------------------------------------------------------------------------
// Kernel 1: W_v [2048,512] fp32 -> Wt4 bf16 in MFMA-B-fragment order
// (R11/R13-verified): ushort idx = ((kt*32 + f)*64 + g*16 + lr)*8 + e,
// f=col>>4, lr=col&15, kt=k>>5, g=(k>>3)&3, e=k&7. One wave B-frag load
// = contiguous 1KB global_load_dwordx4 (L2-resident).
// ---------------------------------------------------------------------------
__global__ __launch_bounds__(256) void k_prepW(const float* __restrict__ Wv,
                                               unsigned short* __restrict__ Wt4) {
    __shared__ float tile[64][65];
    int kb = blockIdx.x >> 3, ct = blockIdx.x & 7;
    int k0 = kb * 64, c0 = ct * 64;
    int t = threadIdx.x;
    int cl = t & 63, rq = t >> 6;
#pragma unroll
    for (int i = 0; i < 16; ++i) {
        int r = rq * 16 + i;
        tile[r][cl] = Wv[(size_t)(k0 + r) * H_SZ + c0 + cl];
    }
    __syncthreads();
    int kl = t & 63;
#pragma unroll
    for (int i = 0; i < 16; ++i) {
        int cr = rq * 16 + i;
        int col = c0 + cr;
        int k = k0 + kl;
        int f = col >> 4, lr = col & 15;
        int kt = k >> 5, g = (k >> 3) & 3, e = k & 7;
        size_t dst = ((size_t)(kt * 32 + f) * 64 + g * 16 + lr) * 8 + e;
        Wt4[dst] = f2bf(tile[kl][cr]);
    }
}

// ---------------------------------------------------------------------------
// Kernel 2: base[b,h] = h_att[b]@W_ha + prev_h2[b]@W_hv + b_ha + b_hv + b_v
// ---------------------------------------------------------------------------
__global__ __launch_bounds__(256) void k_base(const float* __restrict__ h_att,
                                              const float* __restrict__ prev_h2,
                                              const float* __restrict__ W_ha,
                                              const float* __restrict__ b_ha,
                                              const float* __restrict__ W_hv,
                                              const float* __restrict__ b_hv,
                                              const float* __restrict__ b_v,
                                              float* __restrict__ base_g) {
    __shared__ float ha_s[4][RNN];
    __shared__ float pv_s[4][RNN];
    int bg = blockIdx.x >> 2, hg = blockIdx.x & 3;
    int t = threadIdx.x;
#pragma unroll
    for (int i = 0; i < 16; ++i) {
        int idx = i * 256 + t;
        int bl = idx >> 10, k = idx & 1023;
        ha_s[bl][k] = h_att[(size_t)(bg * 4 + bl) * RNN + k];
        pv_s[bl][k] = prev_h2[(size_t)(bg * 4 + bl) * RNN + k];
    }
    __syncthreads();
    int h = hg * 128 + (t & 127);
    int br = t >> 7;
    float aA0 = 0, aA1 = 0, aV0 = 0, aV1 = 0;
#pragma unroll 4
    for (int k = 0; k < RNN; ++k) {
        float w1 = W_ha[(size_t)k * H_SZ + h];
        float w2 = W_hv[(size_t)k * H_SZ + h];
        aA0 = fmaf(ha_s[br * 2][k],     w1, aA0);
        aA1 = fmaf(ha_s[br * 2 + 1][k], w1, aA1);
        aV0 = fmaf(pv_s[br * 2][k],     w2, aV0);
        aV1 = fmaf(pv_s[br * 2 + 1][k], w2, aV1);
    }
    float bias = b_ha[h] + b_hv[h] + b_v[h];
    base_g[(size_t)(bg * 4 + br * 2) * H_SZ + h]     = aA0 + aV0 + bias;
    base_g[(size_t)(bg * 4 + br * 2 + 1) * H_SZ + h] = aA1 + aV1 + bias;
}

// ---------------------------------------------------------------------------
// Kernel 3 (R19): flat-M GEMM + fused score, R16's kstep loop restored to a
// SPLIT grid: 392 blocks x 128 flat rows (zero padding waste; spans <=2 b).
// 1024 thr = 16 waves (2M x 8N), wave 64x64, acc[4][4]=64 AGPR + 64 VGPR ->
// LDS 21KB, 128 regs -> TWO blocks/CU co-resident (32 waves): barrier/drain
// stalls of one block overlap the other's compute (m114), which the fused
// grid=256 design structurally lacked. A: bf16 LDS dbuf (R16 swizzle);
// B: register-direct 4 frags from L2-hot fragment-packed Wt4; 1 barrier/kt.
// ---------------------------------------------------------------------------
__global__ __launch_bounds__(1024, 8) void k_gemm(const float* __restrict__ imgs,
                                                  const unsigned short* __restrict__ Wt4,
                                                  const float* __restrict__ base_g,
                                                  const float* __restrict__ W_f,
                                                  float* __restrict__ att_g) {
    __shared__ __align__(16) short A_s[2][BM * 32];   // 2 x 8 KB
    __shared__ float att_part[8][BM];

    const int m0 = blockIdx.x * BM;
    const int t = threadIdx.x;
    const int lane = t & 63, w = t >> 6;
    const int wm = w >> 3, wn = w & 7;           // 2M x 8N wave grid
    const int lr = lane & 15, g = lane >> 4;

    const char* Bp = (const char*)Wt4 + ((size_t)(wn * 4) * 64 + lane) * 16;

    // ---- A staging map: thread -> local row t>>3, chunk t&7 (4 floats) ----
    const int arow = t >> 3, ac = t & 7;
    const float* Ag = imgs + (size_t)(m0 + arow) * DVD + ac * 4;
    const unsigned awr = (unsigned)(arow * 64 +
        ((((ac >> 1) ^ ((arow ^ (arow >> 2)) & 3)) << 4) | ((ac & 1) << 3)));

    // ---- A fragment read addresses (R16 swizzle) ----
    unsigned ard[4];
#pragma unroll
    for (int mf = 0; mf < 4; ++mf) {
        int r = wm * 64 + mf * 16 + lr;
        ard[mf] = (unsigned)(r * 64 + ((g ^ ((r ^ (r >> 2)) & 3)) << 4));
    }

    f32x4 acc[4][4] = {};
    f32x4 rA;
    s16x8 bR[4];

    auto ldA = [&](int kt) {
        rA = *(const f32x4*)(Ag + (size_t)kt * 32);
    };
    auto wrA = [&](int buf) {
        u32x2 pk;
        pk[0] = cvt2(rA[0], rA[1]);
        pk[1] = cvt2(rA[2], rA[3]);
        *(u32x2*)((char*)A_s[buf] + awr) = pk;    // auto vmcnt wait on rA
    };
    auto ldB = [&](int kt) {
        const char* p = Bp + (size_t)kt * 32768;
#pragma unroll
        for (int n = 0; n < 4; ++n)
            bR[n] = *(const s16x8*)(p + n * 1024);
    };

    // ---- prologue: B(0), A(0)->LDS buf0 ----
    ldB(0);
    ldA(0);
    wrA(0);
    asm volatile("s_waitcnt lgkmcnt(0)" ::: "memory");
    __builtin_amdgcn_sched_barrier(0);
    __builtin_amdgcn_s_barrier();

    // ---- K loop: 1 barrier/kstep (R16-proven) ----
    for (int kt = 0; kt < NKT; ++kt) {
        if (kt + 1 < NKT) ldA(kt + 1);           // HBM, lands by wrA below
        const char* Ac = (const char*)A_s[kt & 1];
        s16x8 aF[4];
#pragma unroll
        for (int mf = 0; mf < 4; ++mf)
            aF[mf] = *(const s16x8*)(Ac + ard[mf]);
        __builtin_amdgcn_s_setprio(1);
#pragma unroll
        for (int mf = 0; mf < 4; ++mf)
#pragma unroll
            for (int n = 0; n < 4; ++n)
                acc[mf][n] = __builtin_amdgcn_mfma_f32_16x16x32_bf16(
                    aF[mf], bR[n], acc[mf][n], 0, 0, 0);
        __builtin_amdgcn_s_setprio(0);
        if (kt + 1 < NKT) {
            ldB(kt + 1);                         // WAR reload, L2/L1
            wrA((kt + 1) & 1);                   // waits rA (auto vmcnt)
            asm volatile("s_waitcnt lgkmcnt(0)" ::: "memory");
            __builtin_amdgcn_sched_barrier(0);
            __builtin_amdgcn_s_barrier();
        }
    }

    // ---- score epilogue: this wave's 64 cols -> att_part[wn][row] ----
    const int b0 = m0 / A_RG;
    const int b1 = min(b0 + 1, B_SZ - 1);
    {
        float wfv[4], bs0[4], bs1[4];
#pragma unroll
        for (int n = 0; n < 4; ++n) {
            int col = wn * 64 + n * 16 + lr;
            wfv[n] = W_f[col];
            bs0[n] = base_g[(size_t)b0 * H_SZ + col];
            bs1[n] = base_g[(size_t)b1 * H_SZ + col];
        }
#pragma unroll
        for (int mf = 0; mf < 4; ++mf) {
            float pj[4] = {0.f, 0.f, 0.f, 0.f};
#pragma unroll
            for (int j = 0; j < 4; ++j) {
                int row = wm * 64 + mf * 16 + g * 4 + j;
                bool second = (m0 + row) >= (b0 + 1) * A_RG;
#pragma unroll
                for (int n = 0; n < 4; ++n) {
                    float bsv = second ? bs1[n] : bs0[n];
                    pj[j] = fmaf(fmaxf(acc[mf][n][j] + bsv, 0.f), wfv[n], pj[j]);
                }
            }
#pragma unroll
            for (int j = 0; j < 4; ++j) {
                float s = pj[j];
                s += __shfl_xor(s, 1);
                s += __shfl_xor(s, 2);
                s += __shfl_xor(s, 4);
                s += __shfl_xor(s, 8);   // 16 lr-lanes of this row
                if (lr == 0)
                    att_part[wn][wm * 64 + mf * 16 + g * 4 + j] = s;
            }
        }
    }
    __syncthreads();

    if (t < BM) {
        float s = 0.f;
#pragma unroll
        for (int q = 0; q < 8; ++q) s += att_part[q][t];
        att_g[m0 + t] = s;
    }
}

// ---------------------------------------------------------------------------
// Kernel 4: softmax over A=196 + weighted sum (R9-verified). grid
// (2 d-halves, 256 b), block 256; thread owns one f32x4 col group,
// 4 rotating accumulators.
// ---------------------------------------------------------------------------
__global__ __launch_bounds__(256) void k_ws(const float* __restrict__ imgs,
                                            const float* __restrict__ att_g,
                                            float* __restrict__ out) {
    __shared__ float alpha_s[A_RG];
    int b = blockIdx.y, dc = blockIdx.x;
    int t = threadIdx.x;

    if (t < 64) {
        float v[4], e[4];
        float mx = -1e30f;
#pragma unroll
        for (int i = 0; i < 4; ++i) {
            int r = i * 64 + t;
            v[i] = (r < A_RG) ? att_g[(size_t)b * A_RG + r] : -1e30f;
            mx = fmaxf(mx, v[i]);
        }
        for (int d = 1; d < 64; d <<= 1) mx = fmaxf(mx, __shfl_xor(mx, d));
        float sum = 0.f;
#pragma unroll
        for (int i = 0; i < 4; ++i) {
            int r = i * 64 + t;
            e[i] = (r < A_RG) ? __expf(v[i] - mx) : 0.f;
            sum += e[i];
        }
        for (int d = 1; d < 64; d <<= 1) sum += __shfl_xor(sum, d);
        float inv = 1.0f / sum;
#pragma unroll
        for (int i = 0; i < 4; ++i) {
            int r = i * 64 + t;
            if (r < A_RG) alpha_s[r] = e[i] * inv;
        }
    }
    __syncthreads();

    const float* ib = imgs + (size_t)b * A_RG * DVD + dc * 1024 + t * 4;
    f32x4 o0 = {}, o1 = {}, o2 = {}, o3 = {};
    for (int a = 0; a < A_RG; a += 4) {           // 196 = 49*4 exact
        float al0 = alpha_s[a],     al1 = alpha_s[a + 1];
        float al2 = alpha_s[a + 2], al3 = alpha_s[a + 3];
        f32x4 v0 = *(const f32x4*)(ib + (size_t)(a)     * DVD);
        f32x4 v1 = *(const f32x4*)(ib + (size_t)(a + 1) * DVD);
        f32x4 v2 = *(const f32x4*)(ib + (size_t)(a + 2) * DVD);
        f32x4 v3 = *(const f32x4*)(ib + (size_t)(a + 3) * DVD);
#pragma unroll
        for (int j = 0; j < 4; ++j) {
            o0[j] = fmaf(al0, v0[j], o0[j]);
            o1[j] = fmaf(al1, v1[j], o1[j]);
            o2[j] = fmaf(al2, v2[j], o2[j]);
            o3[j] = fmaf(al3, v3[j], o3[j]);
        }
    }
    f32x4 o;
#pragma unroll
    for (int j = 0; j < 4; ++j) o[j] = (o0[j] + o1[j]) + (o2[j] + o3[j]);
    *(f32x4*)(out + (size_t)b * DVD + dc * 1024 + t * 4) = o;
}

// ---------------------------------------------------------------------------
extern "C" void kernel_launch(void* const* d_in, const int* in_sizes, int n_in,
                              void* d_out, int out_size, void* d_ws, size_t ws_size,
                              hipStream_t stream) {
    const float* h_att   = (const float*)d_in[0];
    const float* prev_h2 = (const float*)d_in[1];
    const float* imgs    = (const float*)d_in[2];
    const float* W_v     = (const float*)d_in[3];
    const float* b_v     = (const float*)d_in[4];
    const float* W_ha    = (const float*)d_in[5];
    const float* b_ha    = (const float*)d_in[6];
    const float* W_hv    = (const float*)d_in[7];
    const float* b_hv    = (const float*)d_in[8];
    const float* W_f     = (const float*)d_in[9];
    // d_in[10] = b_f: softmax-invariant additive constant -> unused

    // ws layout: [0,2MB) Wt4 bf16 fragment-packed; [2MB,+512KB) base fp32
    // [256][512]; then att fp32 [50176]
    unsigned short* Wt4 = (unsigned short*)d_ws;
    float* base_g = (float*)((char*)d_ws + (size_t)DVD * H_SZ * 2);
    float* att_g  = (float*)((char*)d_ws + (size_t)DVD * H_SZ * 2 + (size_t)B_SZ * H_SZ * 4);
    float* out = (float*)d_out;

    hipLaunchKernelGGL(k_prepW, dim3(256), dim3(256), 0, stream, W_v, Wt4);
    hipLaunchKernelGGL(k_base, dim3(256), dim3(256), 0, stream,
                       h_att, prev_h2, W_ha, b_ha, W_hv, b_hv, b_v, base_g);
    hipLaunchKernelGGL(k_gemm, dim3(NBLK), dim3(1024), 0, stream,
                       imgs, Wt4, base_g, W_f, att_g);
    hipLaunchKernelGGL(k_ws, dim3(2, B_SZ), dim3(256), 0, stream,
                       imgs, att_g, out);
}

// Round 20
// 351.992 us; speedup vs baseline: 6.7760x; 6.7760x over previous
//
#include <hip/hip_runtime.h>
#include <stdint.h>

typedef float f32x4 __attribute__((ext_vector_type(4)));
typedef short s16x8 __attribute__((ext_vector_type(8)));
typedef unsigned u32x2 __attribute__((ext_vector_type(2)));

#define B_SZ 256
#define A_RG 196
#define DVD  2048
#define RNN  1024
#define H_SZ 512
#define M_TOT (B_SZ * A_RG)   // 50176 flat rows
#define BM 64
#define NKT  (DVD / 32)       // 64 K-tiles
#define NBLK (M_TOT / BM)     // 784

__device__ __forceinline__ unsigned short f2bf(float f) {
    unsigned u = __builtin_bit_cast(unsigned, f);
    u = u + 0x7FFFu + ((u >> 16) & 1u);   // RNE
    return (unsigned short)(u >> 16);
}

__device__ __forceinline__ unsigned cvt2(float a, float b) {
    unsigned r;
    asm("v_cvt_pk_bf16_f32 %0, %1, %2" : "=v"(r) : "v"(a), "v"(b));
    return r;
}

// ---------------------------------------------------------------------------
// Kernel 1: W_v [2048,512] fp32 -> Wt4 bf16 in MFMA-B-fragment order
// (R11/R13-verified): ushort idx = ((kt*32 + f)*64 + g*16 + lr)*8 + e,
// f=col>>4, lr=col&15, kt=k>>5, g=(k>>3)&3, e=k&7. One wave B-frag load
// = contiguous 1KB global_load_dwordx4 (L2-resident).
// ---------------------------------------------------------------------------
__global__ __launch_bounds__(256) void k_prepW(const float* __restrict__ Wv,
                                               unsigned short* __restrict__ Wt4) {
    __shared__ float tile[64][65];
    int kb = blockIdx.x >> 3, ct = blockIdx.x & 7;
    int k0 = kb * 64, c0 = ct * 64;
    int t = threadIdx.x;
    int cl = t & 63, rq = t >> 6;
#pragma unroll
    for (int i = 0; i < 16; ++i) {
        int r = rq * 16 + i;
        tile[r][cl] = Wv[(size_t)(k0 + r) * H_SZ + c0 + cl];
    }
    __syncthreads();
    int kl = t & 63;
#pragma unroll
    for (int i = 0; i < 16; ++i) {
        int cr = rq * 16 + i;
        int col = c0 + cr;
        int k = k0 + kl;
        int f = col >> 4, lr = col & 15;
        int kt = k >> 5, g = (k >> 3) & 3, e = k & 7;
        size_t dst = ((size_t)(kt * 32 + f) * 64 + g * 16 + lr) * 8 + e;
        Wt4[dst] = f2bf(tile[kl][cr]);
    }
}

// ---------------------------------------------------------------------------
// Kernel 2: base[b,h] = h_att[b]@W_ha + prev_h2[b]@W_hv + b_ha + b_hv + b_v
// ---------------------------------------------------------------------------
__global__ __launch_bounds__(256) void k_base(const float* __restrict__ h_att,
                                              const float* __restrict__ prev_h2,
                                              const float* __restrict__ W_ha,
                                              const float* __restrict__ b_ha,
                                              const float* __restrict__ W_hv,
                                              const float* __restrict__ b_hv,
                                              const float* __restrict__ b_v,
                                              float* __restrict__ base_g) {
    __shared__ float ha_s[4][RNN];
    __shared__ float pv_s[4][RNN];
    int bg = blockIdx.x >> 2, hg = blockIdx.x & 3;
    int t = threadIdx.x;
#pragma unroll
    for (int i = 0; i < 16; ++i) {
        int idx = i * 256 + t;
        int bl = idx >> 10, k = idx & 1023;
        ha_s[bl][k] = h_att[(size_t)(bg * 4 + bl) * RNN + k];
        pv_s[bl][k] = prev_h2[(size_t)(bg * 4 + bl) * RNN + k];
    }
    __syncthreads();
    int h = hg * 128 + (t & 127);
    int br = t >> 7;
    float aA0 = 0, aA1 = 0, aV0 = 0, aV1 = 0;
#pragma unroll 4
    for (int k = 0; k < RNN; ++k) {
        float w1 = W_ha[(size_t)k * H_SZ + h];
        float w2 = W_hv[(size_t)k * H_SZ + h];
        aA0 = fmaf(ha_s[br * 2][k],     w1, aA0);
        aA1 = fmaf(ha_s[br * 2 + 1][k], w1, aA1);
        aV0 = fmaf(pv_s[br * 2][k],     w2, aV0);
        aV1 = fmaf(pv_s[br * 2 + 1][k], w2, aV1);
    }
    float bias = b_ha[h] + b_hv[h] + b_v[h];
    base_g[(size_t)(bg * 4 + br * 2) * H_SZ + h]     = aA0 + aV0 + bias;
    base_g[(size_t)(bg * 4 + br * 2 + 1) * H_SZ + h] = aA1 + aV1 + bias;
}

// ---------------------------------------------------------------------------
// Kernel 3 (R20 = R19 with CORRECT occupancy): flat-M GEMM + fused score.
// 784 blocks x 64 flat rows; 512 thr = 8 waves in 1M x 8N (wave 64x64,
// acc[4][4] = 64 AGPR + ~60 VGPR <= 128-reg cap). __launch_bounds__(512,4)
// -> 4 waves/SIMD -> TWO blocks/CU co-resident: each block's barrier/drain
// stalls overlap the other's compute (m114). R19's (1024,8) forced a 64-reg
// cap -> 5 GB spill; that is the only thing changed here.
// A: bf16 LDS dbuf (R16 swizzle); B: register-direct 4 frags from L2-hot
// fragment-packed Wt4; 1 barrier/kstep (R16-proven loop).
// ---------------------------------------------------------------------------
__global__ __launch_bounds__(512, 4) void k_gemm(const float* __restrict__ imgs,
                                                 const unsigned short* __restrict__ Wt4,
                                                 const float* __restrict__ base_g,
                                                 const float* __restrict__ W_f,
                                                 float* __restrict__ att_g) {
    __shared__ __align__(16) short A_s[2][BM * 32];   // 2 x 4 KB
    __shared__ float att_part[8][BM];

    const int m0 = blockIdx.x * BM;
    const int t = threadIdx.x;
    const int lane = t & 63, w = t >> 6;      // w = wn (1M x 8N)
    const int lr = lane & 15, g = lane >> 4;

    const char* Bp = (const char*)Wt4 + ((size_t)(w * 4) * 64 + lane) * 16;

    // ---- A staging map: thread -> row t>>3 (0..63), chunk t&7 (4 floats) --
    const int arow = t >> 3, ac = t & 7;
    const float* Ag = imgs + (size_t)(m0 + arow) * DVD + ac * 4;
    const unsigned awr = (unsigned)(arow * 64 +
        ((((ac >> 1) ^ ((arow ^ (arow >> 2)) & 3)) << 4) | ((ac & 1) << 3)));

    // ---- A fragment read addresses (R16 swizzle) ----
    unsigned ard[4];
#pragma unroll
    for (int mf = 0; mf < 4; ++mf) {
        int r = mf * 16 + lr;
        ard[mf] = (unsigned)(r * 64 + ((g ^ ((r ^ (r >> 2)) & 3)) << 4));
    }

    f32x4 acc[4][4] = {};
    f32x4 rA;
    s16x8 bR[4];

    auto ldA = [&](int kt) {
        rA = *(const f32x4*)(Ag + (size_t)kt * 32);
    };
    auto wrA = [&](int buf) {
        u32x2 pk;
        pk[0] = cvt2(rA[0], rA[1]);
        pk[1] = cvt2(rA[2], rA[3]);
        *(u32x2*)((char*)A_s[buf] + awr) = pk;    // auto vmcnt wait on rA
    };
    auto ldB = [&](int kt) {
        const char* p = Bp + (size_t)kt * 32768;
#pragma unroll
        for (int n = 0; n < 4; ++n)
            bR[n] = *(const s16x8*)(p + n * 1024);
    };

    // ---- prologue: B(0), A(0)->LDS buf0 ----
    ldB(0);
    ldA(0);
    wrA(0);
    asm volatile("s_waitcnt lgkmcnt(0)" ::: "memory");
    __builtin_amdgcn_sched_barrier(0);
    __builtin_amdgcn_s_barrier();

    // ---- K loop: 1 barrier/kstep (R16-proven) ----
    for (int kt = 0; kt < NKT; ++kt) {
        if (kt + 1 < NKT) ldA(kt + 1);           // HBM, lands by wrA below
        const char* Ac = (const char*)A_s[kt & 1];
        s16x8 aF[4];
#pragma unroll
        for (int mf = 0; mf < 4; ++mf)
            aF[mf] = *(const s16x8*)(Ac + ard[mf]);
        __builtin_amdgcn_s_setprio(1);
#pragma unroll
        for (int mf = 0; mf < 4; ++mf)
#pragma unroll
            for (int n = 0; n < 4; ++n)
                acc[mf][n] = __builtin_amdgcn_mfma_f32_16x16x32_bf16(
                    aF[mf], bR[n], acc[mf][n], 0, 0, 0);
        __builtin_amdgcn_s_setprio(0);
        if (kt + 1 < NKT) {
            ldB(kt + 1);                         // WAR reload, L2/L1
            wrA((kt + 1) & 1);                   // waits rA (auto vmcnt)
            asm volatile("s_waitcnt lgkmcnt(0)" ::: "memory");
            __builtin_amdgcn_sched_barrier(0);
            __builtin_amdgcn_s_barrier();
        }
    }

    // ---- score epilogue: this wave's 64 cols -> att_part[w][row] ----
    const int b0 = m0 / A_RG;
    const int b1 = min(b0 + 1, B_SZ - 1);
    {
        float wfv[4], bs0[4], bs1[4];
#pragma unroll
        for (int n = 0; n < 4; ++n) {
            int col = w * 64 + n * 16 + lr;
            wfv[n] = W_f[col];
            bs0[n] = base_g[(size_t)b0 * H_SZ + col];
            bs1[n] = base_g[(size_t)b1 * H_SZ + col];
        }
#pragma unroll
        for (int mf = 0; mf < 4; ++mf) {
            float pj[4] = {0.f, 0.f, 0.f, 0.f};
#pragma unroll
            for (int j = 0; j < 4; ++j) {
                int row = mf * 16 + g * 4 + j;
                bool second = (m0 + row) >= (b0 + 1) * A_RG;
#pragma unroll
                for (int n = 0; n < 4; ++n) {
                    float bsv = second ? bs1[n] : bs0[n];
                    pj[j] = fmaf(fmaxf(acc[mf][n][j] + bsv, 0.f), wfv[n], pj[j]);
                }
            }
#pragma unroll
            for (int j = 0; j < 4; ++j) {
                float s = pj[j];
                s += __shfl_xor(s, 1);
                s += __shfl_xor(s, 2);
                s += __shfl_xor(s, 4);
                s += __shfl_xor(s, 8);   // 16 lr-lanes of this row
                if (lr == 0)
                    att_part[w][mf * 16 + g * 4 + j] = s;
            }
        }
    }
    __syncthreads();

    if (t < BM) {
        float s = 0.f;
#pragma unroll
        for (int q = 0; q < 8; ++q) s += att_part[q][t];
        att_g[m0 + t] = s;
    }
}

// ---------------------------------------------------------------------------
// Kernel 4: softmax over A=196 + weighted sum (R9-verified). grid
// (2 d-halves, 256 b), block 256; thread owns one f32x4 col group,
// 4 rotating accumulators.
// ---------------------------------------------------------------------------
__global__ __launch_bounds__(256) void k_ws(const float* __restrict__ imgs,
                                            const float* __restrict__ att_g,
                                            float* __restrict__ out) {
    __shared__ float alpha_s[A_RG];
    int b = blockIdx.y, dc = blockIdx.x;
    int t = threadIdx.x;

    if (t < 64) {
        float v[4], e[4];
        float mx = -1e30f;
#pragma unroll
        for (int i = 0; i < 4; ++i) {
            int r = i * 64 + t;
            v[i] = (r < A_RG) ? att_g[(size_t)b * A_RG + r] : -1e30f;
            mx = fmaxf(mx, v[i]);
        }
        for (int d = 1; d < 64; d <<= 1) mx = fmaxf(mx, __shfl_xor(mx, d));
        float sum = 0.f;
#pragma unroll
        for (int i = 0; i < 4; ++i) {
            int r = i * 64 + t;
            e[i] = (r < A_RG) ? __expf(v[i] - mx) : 0.f;
            sum += e[i];
        }
        for (int d = 1; d < 64; d <<= 1) sum += __shfl_xor(sum, d);
        float inv = 1.0f / sum;
#pragma unroll
        for (int i = 0; i < 4; ++i) {
            int r = i * 64 + t;
            if (r < A_RG) alpha_s[r] = e[i] * inv;
        }
    }
    __syncthreads();

    const float* ib = imgs + (size_t)b * A_RG * DVD + dc * 1024 + t * 4;
    f32x4 o0 = {}, o1 = {}, o2 = {}, o3 = {};
    for (int a = 0; a < A_RG; a += 4) {           // 196 = 49*4 exact
        float al0 = alpha_s[a],     al1 = alpha_s[a + 1];
        float al2 = alpha_s[a + 2], al3 = alpha_s[a + 3];
        f32x4 v0 = *(const f32x4*)(ib + (size_t)(a)     * DVD);
        f32x4 v1 = *(const f32x4*)(ib + (size_t)(a + 1) * DVD);
        f32x4 v2 = *(const f32x4*)(ib + (size_t)(a + 2) * DVD);
        f32x4 v3 = *(const f32x4*)(ib + (size_t)(a + 3) * DVD);
#pragma unroll
        for (int j = 0; j < 4; ++j) {
            o0[j] = fmaf(al0, v0[j], o0[j]);
            o1[j] = fmaf(al1, v1[j], o1[j]);
            o2[j] = fmaf(al2, v2[j], o2[j]);
            o3[j] = fmaf(al3, v3[j], o3[j]);
        }
    }
    f32x4 o;
#pragma unroll
    for (int j = 0; j < 4; ++j) o[j] = (o0[j] + o1[j]) + (o2[j] + o3[j]);
    *(f32x4*)(out + (size_t)b * DVD + dc * 1024 + t * 4) = o;
}

// ---------------------------------------------------------------------------
extern "C" void kernel_launch(void* const* d_in, const int* in_sizes, int n_in,
                              void* d_out, int out_size, void* d_ws, size_t ws_size,
                              hipStream_t stream) {
    const float* h_att   = (const float*)d_in[0];
    const float* prev_h2 = (const float*)d_in[1];
    const float* imgs    = (const float*)d_in[2];
    const float* W_v     = (const float*)d_in[3];
    const float* b_v     = (const float*)d_in[4];
    const float* W_ha    = (const float*)d_in[5];
    const float* b_ha    = (const float*)d_in[6];
    const float* W_hv    = (const float*)d_in[7];
    const float* b_hv    = (const float*)d_in[8];
    const float* W_f     = (const float*)d_in[9];
    // d_in[10] = b_f: softmax-invariant additive constant -> unused

    // ws layout: [0,2MB) Wt4 bf16 fragment-packed; [2MB,+512KB) base fp32
    // [256][512]; then att fp32 [50176]
    unsigned short* Wt4 = (unsigned short*)d_ws;
    float* base_g = (float*)((char*)d_ws + (size_t)DVD * H_SZ * 2);
    float* att_g  = (float*)((char*)d_ws + (size_t)DVD * H_SZ * 2 + (size_t)B_SZ * H_SZ * 4);
    float* out = (float*)d_out;

    hipLaunchKernelGGL(k_prepW, dim3(256), dim3(256), 0, stream, W_v, Wt4);
    hipLaunchKernelGGL(k_base, dim3(256), dim3(256), 0, stream,
                       h_att, prev_h2, W_ha, b_ha, W_hv, b_hv, b_v, base_g);
    hipLaunchKernelGGL(k_gemm, dim3(NBLK), dim3(512), 0, stream,
                       imgs, Wt4, base_g, W_f, att_g);
    hipLaunchKernelGGL(k_ws, dim3(2, B_SZ), dim3(256), 0, stream,
                       imgs, att_g, out);
}

// Round 21
// 348.734 us; speedup vs baseline: 6.8393x; 1.0093x over previous
//
#include <hip/hip_runtime.h>
#include <stdint.h>

typedef float f32x4 __attribute__((ext_vector_type(4)));
typedef short s16x8 __attribute__((ext_vector_type(8)));
typedef unsigned u32x2 __attribute__((ext_vector_type(2)));

#define B_SZ 256
#define A_RG 196
#define DVD  2048
#define RNN  1024
#define H_SZ 512
#define NKT  (DVD / 32)       // 64 K-tiles

__device__ __forceinline__ unsigned short f2bf(float f) {
    unsigned u = __builtin_bit_cast(unsigned, f);
    u = u + 0x7FFFu + ((u >> 16) & 1u);   // RNE
    return (unsigned short)(u >> 16);
}

__device__ __forceinline__ unsigned cvt2(float a, float b) {
    unsigned r;
    asm("v_cvt_pk_bf16_f32 %0, %1, %2" : "=v"(r) : "v"(a), "v"(b));
    return r;
}

// ---------------------------------------------------------------------------
// Kernel 1: W_v [2048,512] fp32 -> Wt4 bf16 in MFMA-B-fragment order
// (R11/R13-verified): ushort idx = ((kt*32 + f)*64 + g*16 + lr)*8 + e,
// f=col>>4, lr=col&15, kt=k>>5, g=(k>>3)&3, e=k&7.
// ---------------------------------------------------------------------------
__global__ __launch_bounds__(256) void k_prepW(const float* __restrict__ Wv,
                                               unsigned short* __restrict__ Wt4) {
    __shared__ float tile[64][65];
    int kb = blockIdx.x >> 3, ct = blockIdx.x & 7;
    int k0 = kb * 64, c0 = ct * 64;
    int t = threadIdx.x;
    int cl = t & 63, rq = t >> 6;
#pragma unroll
    for (int i = 0; i < 16; ++i) {
        int r = rq * 16 + i;
        tile[r][cl] = Wv[(size_t)(k0 + r) * H_SZ + c0 + cl];
    }
    __syncthreads();
    int kl = t & 63;
#pragma unroll
    for (int i = 0; i < 16; ++i) {
        int cr = rq * 16 + i;
        int col = c0 + cr;
        int k = k0 + kl;
        int f = col >> 4, lr = col & 15;
        int kt = k >> 5, g = (k >> 3) & 3, e = k & 7;
        size_t dst = ((size_t)(kt * 32 + f) * 64 + g * 16 + lr) * 8 + e;
        Wt4[dst] = f2bf(tile[kl][cr]);
    }
}

// ---------------------------------------------------------------------------
// Kernel 2: base[b,h] = h_att[b]@W_ha + prev_h2[b]@W_hv + b_ha + b_hv + b_v
// ---------------------------------------------------------------------------
__global__ __launch_bounds__(256) void k_base(const float* __restrict__ h_att,
                                              const float* __restrict__ prev_h2,
                                              const float* __restrict__ W_ha,
                                              const float* __restrict__ b_ha,
                                              const float* __restrict__ W_hv,
                                              const float* __restrict__ b_hv,
                                              const float* __restrict__ b_v,
                                              float* __restrict__ base_g) {
    __shared__ float ha_s[4][RNN];
    __shared__ float pv_s[4][RNN];
    int bg = blockIdx.x >> 2, hg = blockIdx.x & 3;
    int t = threadIdx.x;
#pragma unroll
    for (int i = 0; i < 16; ++i) {
        int idx = i * 256 + t;
        int bl = idx >> 10, k = idx & 1023;
        ha_s[bl][k] = h_att[(size_t)(bg * 4 + bl) * RNN + k];
        pv_s[bl][k] = prev_h2[(size_t)(bg * 4 + bl) * RNN + k];
    }
    __syncthreads();
    int h = hg * 128 + (t & 127);
    int br = t >> 7;
    float aA0 = 0, aA1 = 0, aV0 = 0, aV1 = 0;
#pragma unroll 4
    for (int k = 0; k < RNN; ++k) {
        float w1 = W_ha[(size_t)k * H_SZ + h];
        float w2 = W_hv[(size_t)k * H_SZ + h];
        aA0 = fmaf(ha_s[br * 2][k],     w1, aA0);
        aA1 = fmaf(ha_s[br * 2 + 1][k], w1, aA1);
        aV0 = fmaf(pv_s[br * 2][k],     w2, aV0);
        aV1 = fmaf(pv_s[br * 2 + 1][k], w2, aV1);
    }
    float bias = b_ha[h] + b_hv[h] + b_v[h];
    base_g[(size_t)(bg * 4 + br * 2) * H_SZ + h]     = aA0 + aV0 + bias;
    base_g[(size_t)(bg * 4 + br * 2 + 1) * H_SZ + h] = aA1 + aV1 + bias;
}

// ---------------------------------------------------------------------------
// Kernel 3 (fused, R21 = R16 + depth-2 A prefetch ONLY): 1024 thr = 16
// waves (2M x 8N), wave 64x64, acc[4][4]=64 AGPR, 128-reg cap. A: bf16 LDS
// dbuf (R16's verified swizzle) with rA loads now issued a FULL kstep before
// their ds_write (window ~1.5 ksteps > 900cy HBM latency, the R17-quantified
// exposed stall). B: register-direct 4 frags from L2-hot fragment-packed
// Wt4, WAR reloads. 1 barrier/kstep. Score -> online softmax -> V accumulate
// (R13/R16-verified, unchanged).
// ---------------------------------------------------------------------------
__global__ __launch_bounds__(1024, 4) void k_fused(const float* __restrict__ imgs,
                                                   const unsigned short* __restrict__ Wt4,
                                                   const float* __restrict__ base_g,
                                                   const float* __restrict__ W_f,
                                                   float* __restrict__ out) {
    __shared__ __align__(16) short A_s[2][128 * 32];   // 2 x 8 KB
    __shared__ float att_part[8][128];
    __shared__ float e_s[128];
    __shared__ float scal_r;
    __shared__ float scal_l;

    const int b = blockIdx.x;
    const int t = threadIdx.x;
    const int lane = t & 63, w = t >> 6;
    const int wm = w >> 3, wn = w & 7;           // 2M x 8N wave grid
    const int lr = lane & 15, g = lane >> 4;

    const float* imgb = imgs + (size_t)b * A_RG * DVD;
    const char* Bp = (const char*)Wt4 + ((size_t)(wn * 4) * 64 + lane) * 16;

    float o0 = 0.f, o1 = 0.f;           // thread owns out cols 2t, 2t+1
    float m_run = -1e30f, l_run = 0.f;  // live in wave 0

    // ---- A staging map: thread -> local row t>>3, chunk t&7 (4 floats) ----
    const int arow = t >> 3, ac = t & 7;
    const unsigned awr = (unsigned)(arow * 64 +
        ((((ac >> 1) ^ ((arow ^ (arow >> 2)) & 3)) << 4) | ((ac & 1) << 3)));

    // ---- A fragment read addresses ----
    unsigned ard[4];
#pragma unroll
    for (int mf = 0; mf < 4; ++mf) {
        int r = wm * 64 + mf * 16 + lr;
        ard[mf] = (unsigned)(r * 64 + ((g ^ ((r ^ (r >> 2)) & 3)) << 4));
    }

    for (int at = 0; at < 2; ++at) {
        const bool last = (at == 1);
        const int m0 = at * 128;

        const float* Ag = imgb + (size_t)min(m0 + arow, A_RG - 1) * DVD + ac * 4;

        f32x4 acc[4][4] = {};
        f32x4 rAe, rAo;
        s16x8 bR[4];

        auto ldA = [&](int kt, f32x4& r) {
            r = *(const f32x4*)(Ag + (size_t)kt * 32);
        };
        auto wrA = [&](int buf, const f32x4& r) {
            u32x2 pk;
            pk[0] = cvt2(r[0], r[1]);
            pk[1] = cvt2(r[2], r[3]);
            *(u32x2*)((char*)A_s[buf] + awr) = pk;   // counted vmcnt wait on r
        };
        auto ldB = [&](int kt) {
            const char* p = Bp + (size_t)kt * 32768;
#pragma unroll
            for (int n = 0; n < 4; ++n)
                bR[n] = *(const s16x8*)(p + n * 1024);
        };
        auto compute = [&](int buf) {
            const char* Ac = (const char*)A_s[buf];
            s16x8 aF[4];
#pragma unroll
            for (int mf = 0; mf < 4; ++mf)
                aF[mf] = *(const s16x8*)(Ac + ard[mf]);
            __builtin_amdgcn_s_setprio(1);
#pragma unroll
            for (int mf = 0; mf < 4; ++mf)
#pragma unroll
                for (int n = 0; n < 4; ++n)
                    acc[mf][n] = __builtin_amdgcn_mfma_f32_16x16x32_bf16(
                        aF[mf], bR[n], acc[mf][n], 0, 0, 0);
            __builtin_amdgcn_s_setprio(0);
        };
        auto fence = [&]() {
            asm volatile("s_waitcnt lgkmcnt(0)" ::: "memory");
            __builtin_amdgcn_sched_barrier(0);
            __builtin_amdgcn_s_barrier();
        };

        // ---- prologue: B(0); A(0)->buf0 now; A(1) in-flight in rAo ----
        ldB(0);
        ldA(0, rAe);
        wrA(0, rAe);
        ldA(1, rAo);
        fence();

        // ---- K loop: kstep kt issues A(kt+2), writes A(kt+1) loaded a
        //      full kstep earlier (window ~1.5 ksteps > HBM latency) ----
        for (int kt = 0; kt < NKT - 2; kt += 2) {
            ldA(kt + 2, rAe);            // even kstep: load ahead into rAe
            compute(kt & 1);
            ldB(kt + 1);                 // WAR reload, L2/L1
            wrA((kt + 1) & 1, rAo);      // A(kt+1), issued last kstep
            fence();
            ldA(kt + 3, rAo);            // odd kstep: load ahead into rAo
            compute((kt + 1) & 1);
            ldB(kt + 2);
            wrA((kt + 2) & 1, rAe);      // A(kt+2), issued this pair's top
            fence();
        }
        // ---- tail kstep NKT-2: write A(NKT-1) (in rAo), no more loads ----
        compute((NKT - 2) & 1);
        ldB(NKT - 1);
        wrA((NKT - 1) & 1, rAo);
        fence();
        // ---- tail kstep NKT-1: compute only ----
        compute((NKT - 1) & 1);

        // ---- score epilogue: this wave's 64 cols -> att_part[wn][row] ----
        {
            float wfv[4], bs[4];
#pragma unroll
            for (int n = 0; n < 4; ++n) {
                int col = wn * 64 + n * 16 + lr;
                wfv[n] = W_f[col];
                bs[n] = base_g[(size_t)b * H_SZ + col];
            }
#pragma unroll
            for (int mf = 0; mf < 4; ++mf) {
                float pj[4] = {0.f, 0.f, 0.f, 0.f};
#pragma unroll
                for (int n = 0; n < 4; ++n) {
                    float a0 = fmaxf(acc[mf][n][0] + bs[n], 0.f);
                    float a1 = fmaxf(acc[mf][n][1] + bs[n], 0.f);
                    float a2 = fmaxf(acc[mf][n][2] + bs[n], 0.f);
                    float a3 = fmaxf(acc[mf][n][3] + bs[n], 0.f);
                    pj[0] = fmaf(a0, wfv[n], pj[0]);
                    pj[1] = fmaf(a1, wfv[n], pj[1]);
                    pj[2] = fmaf(a2, wfv[n], pj[2]);
                    pj[3] = fmaf(a3, wfv[n], pj[3]);
                }
#pragma unroll
                for (int j = 0; j < 4; ++j) {
                    float s = pj[j];
                    s += __shfl_xor(s, 1);
                    s += __shfl_xor(s, 2);
                    s += __shfl_xor(s, 4);
                    s += __shfl_xor(s, 8);   // 16 lr-lanes of this row
                    if (lr == 0)
                        att_part[wn][wm * 64 + mf * 16 + g * 4 + j] = s;
                }
            }
        }
        __builtin_amdgcn_s_barrier();

        // ---- wave 0: online-softmax state update ----
        if (w == 0) {
            int gr0 = m0 + lane, gr1 = m0 + lane + 64;
            float s0, s1;
            {
                float a = 0.f, c = 0.f;
#pragma unroll
                for (int q = 0; q < 8; ++q) {
                    a += att_part[q][lane];
                    c += att_part[q][lane + 64];
                }
                s0 = (gr0 < A_RG) ? a : -1e30f;
                s1 = (gr1 < A_RG) ? c : -1e30f;
            }
            float mx = fmaxf(s0, s1);
            for (int d = 1; d < 64; d <<= 1) mx = fmaxf(mx, __shfl_xor(mx, d));
            float m_new = fmaxf(m_run, mx);
            float r = __expf(m_run - m_new);
            float e0 = __expf(s0 - m_new);
            float e1 = __expf(s1 - m_new);
            float es = e0 + e1;
            for (int d = 1; d < 64; d <<= 1) es += __shfl_xor(es, d);
            l_run = l_run * r + es;
            m_run = m_new;
            e_s[lane] = e0;
            e_s[lane + 64] = e1;
            if (lane == 0) {
                scal_r = r;
                if (last) scal_l = l_run;
            }
        }
        __builtin_amdgcn_s_barrier();

        // ---- V phase: o = o*r + sum_a e[a] * imgs[b, m0+a, 2t..2t+1] ----
        {
            float r = scal_r;
            o0 *= r; o1 *= r;
            const float2* vb = (const float2*)imgb + t;
            const int AV = last ? (A_RG - 128) : 128;   // 68 or 128
#pragma unroll 4
            for (int a = 0; a < AV; ++a) {
                float e = e_s[a];
                float2 v = vb[(size_t)(m0 + a) * (DVD / 2)];
                o0 = fmaf(e, v.x, o0);
                o1 = fmaf(e, v.y, o1);
            }
        }
        // cross-tile LDS hazards covered by tile1's prologue fences
        // (R13/R16-verified pattern).
    }

    // ---- finalize: out[b, 2t..2t+1] = o / l ----
    float linv = 1.0f / scal_l;
    float2 res = make_float2(o0 * linv, o1 * linv);
    ((float2*)(out + (size_t)b * DVD))[t] = res;
}

// ---------------------------------------------------------------------------
extern "C" void kernel_launch(void* const* d_in, const int* in_sizes, int n_in,
                              void* d_out, int out_size, void* d_ws, size_t ws_size,
                              hipStream_t stream) {
    const float* h_att   = (const float*)d_in[0];
    const float* prev_h2 = (const float*)d_in[1];
    const float* imgs    = (const float*)d_in[2];
    const float* W_v     = (const float*)d_in[3];
    const float* b_v     = (const float*)d_in[4];
    const float* W_ha    = (const float*)d_in[5];
    const float* b_ha    = (const float*)d_in[6];
    const float* W_hv    = (const float*)d_in[7];
    const float* b_hv    = (const float*)d_in[8];
    const float* W_f     = (const float*)d_in[9];
    // d_in[10] = b_f: softmax-invariant additive constant -> unused

    // ws layout: [0,2MB) Wt4 bf16 fragment-packed; [2MB,+512KB) base fp32
    unsigned short* Wt4 = (unsigned short*)d_ws;
    float* base_g = (float*)((char*)d_ws + (size_t)DVD * H_SZ * 2);
    float* out = (float*)d_out;

    hipLaunchKernelGGL(k_prepW, dim3(256), dim3(256), 0, stream, W_v, Wt4);
    hipLaunchKernelGGL(k_base, dim3(256), dim3(256), 0, stream,
                       h_att, prev_h2, W_ha, b_ha, W_hv, b_hv, b_v, base_g);
    hipLaunchKernelGGL(k_fused, dim3(B_SZ), dim3(1024), 0, stream,
                       imgs, Wt4, base_g, W_f, out);
}

// Round 22
// 271.762 us; speedup vs baseline: 8.7764x; 1.2832x over previous
//
#include <hip/hip_runtime.h>
#include <stdint.h>

typedef float f32x4 __attribute__((ext_vector_type(4)));
typedef short s16x8 __attribute__((ext_vector_type(8)));
typedef unsigned u32x2 __attribute__((ext_vector_type(2)));
typedef unsigned u32x4 __attribute__((ext_vector_type(4)));

#define B_SZ 256
#define A_RG 196
#define DVD  2048
#define RNN  1024
#define H_SZ 512
#define NKT  (DVD / 32)       // 64 K-tiles

__device__ __forceinline__ unsigned cvt2(float a, float b) {
    unsigned r;
    asm("v_cvt_pk_bf16_f32 %0, %1, %2" : "=v"(r) : "v"(a), "v"(b));
    return r;
}

// ---------------------------------------------------------------------------
// Kernel 1 (R22): W_v [2048,512] fp32 -> Wt4 bf16, MFMA-B-fragment order
// (R11/R13-verified layout), now with PACKED 16B stores: thread handles
// chunk (gg,cr): 8 k-elems of one col -> one global_store_dwordx4.
// chunk slot = (kt*32 + f)*64 + g*16 + lr with kt=kb*2+(gg>>2), g=gg&3,
// f=(c0+cr)>>4, lr=(c0+cr)&15  (identical algebra to the elementwise form).
// ---------------------------------------------------------------------------
__global__ __launch_bounds__(256) void k_prepW(const float* __restrict__ Wv,
                                               unsigned short* __restrict__ Wt4) {
    __shared__ float tile[64][65];
    int kb = blockIdx.x >> 3, ct = blockIdx.x & 7;
    int k0 = kb * 64, c0 = ct * 64;
    int t = threadIdx.x;
    int cl = t & 63, rq = t >> 6;
#pragma unroll
    for (int i = 0; i < 16; ++i) {
        int r = rq * 16 + i;
        tile[r][cl] = Wv[(size_t)(k0 + r) * H_SZ + c0 + cl];
    }
    __syncthreads();
#pragma unroll
    for (int half = 0; half < 2; ++half) {
        int cid = half * 256 + t;          // 0..511
        int gg = cid >> 6, cr = cid & 63;  // k-group (8 elems), local col
        int col = c0 + cr;
        int kt = kb * 2 + (gg >> 2), g = gg & 3;
        int f = col >> 4, lr = col & 15;
        size_t slot = ((size_t)(kt * 32 + f) * 64 + g * 16 + lr);
        u32x4 pk;
#pragma unroll
        for (int p = 0; p < 4; ++p)
            pk[p] = cvt2(tile[gg * 8 + 2 * p][cr], tile[gg * 8 + 2 * p + 1][cr]);
        *(u32x4*)(Wt4 + slot * 8) = pk;
    }
}

// ---------------------------------------------------------------------------
// Kernel 2 (R22): base[b,h] = h_att[b]@W_ha + prev_h2[b]@W_hv + biases.
// Rebuilt for occupancy: grid (4 hg, 256 b) = 1024 blocks (4 blocks/CU,
// 16 waves/CU vs R21's 1 wave/SIMD), block 256 = 128 h x 2 k-halves;
// vectors staged in LDS, 512-iter unroll-8 loop (wave reads 256B-contig
// W rows), LDS reduce across k-halves. L2-BW bound ~15us.
// ---------------------------------------------------------------------------
__global__ __launch_bounds__(256) void k_base(const float* __restrict__ h_att,
                                              const float* __restrict__ prev_h2,
                                              const float* __restrict__ W_ha,
                                              const float* __restrict__ b_ha,
                                              const float* __restrict__ W_hv,
                                              const float* __restrict__ b_hv,
                                              const float* __restrict__ b_v,
                                              float* __restrict__ base_g) {
    __shared__ float ha_s[RNN];
    __shared__ float pv_s[RNN];
    __shared__ float redA[128];
    __shared__ float redV[128];

    const int hg = blockIdx.x;            // 0..3
    const int b  = blockIdx.y;            // 0..255
    const int t  = threadIdx.x;

    for (int i = t; i < RNN; i += 256) {
        ha_s[i] = h_att[(size_t)b * RNN + i];
        pv_s[i] = prev_h2[(size_t)b * RNN + i];
    }
    __syncthreads();

    const int h  = hg * 128 + (t & 127);
    const int ks = t >> 7;                // 0..1 -> k-half
    const int kb = ks * 512;
    const float* Wa = W_ha + (size_t)kb * H_SZ + h;
    const float* Wv = W_hv + (size_t)kb * H_SZ + h;

    float aA = 0.f, aV = 0.f;
#pragma unroll 8
    for (int k = 0; k < 512; ++k) {
        aA = fmaf(ha_s[kb + k], Wa[(size_t)k * H_SZ], aA);
        aV = fmaf(pv_s[kb + k], Wv[(size_t)k * H_SZ], aV);
    }

    if (ks == 1) { redA[t & 127] = aA; redV[t & 127] = aV; }
    __syncthreads();
    if (ks == 0) {
        float s = aA + aV + redA[t] + redV[t] + b_ha[h] + b_hv[h] + b_v[h];
        base_g[(size_t)b * H_SZ + h] = s;
    }
}

// ---------------------------------------------------------------------------
// Kernel 3 (fused, R16-exact — best measured at ~255us): 1024 thr = 16
// waves (2M x 8N), wave 64x64, acc[4][4]=64 AGPR + ~60 VGPR, 128-reg cap.
// A: bf16 LDS dbuf (verified swizzle), single-rA staging; B: register-
// direct 4 frags from L2-hot fragment-packed Wt4, WAR reloads; 1 barrier
// per kstep. Score -> online softmax -> V accumulate (R13-verified).
// ---------------------------------------------------------------------------
__global__ __launch_bounds__(1024, 4) void k_fused(const float* __restrict__ imgs,
                                                   const unsigned short* __restrict__ Wt4,
                                                   const float* __restrict__ base_g,
                                                   const float* __restrict__ W_f,
                                                   float* __restrict__ out) {
    __shared__ __align__(16) short A_s[2][128 * 32];   // 2 x 8 KB
    __shared__ float att_part[8][128];
    __shared__ float e_s[128];
    __shared__ float scal_r;
    __shared__ float scal_l;

    const int b = blockIdx.x;
    const int t = threadIdx.x;
    const int lane = t & 63, w = t >> 6;
    const int wm = w >> 3, wn = w & 7;           // 2M x 8N wave grid
    const int lr = lane & 15, g = lane >> 4;

    const float* imgb = imgs + (size_t)b * A_RG * DVD;
    const char* Bp = (const char*)Wt4 + ((size_t)(wn * 4) * 64 + lane) * 16;

    float o0 = 0.f, o1 = 0.f;           // thread owns out cols 2t, 2t+1
    float m_run = -1e30f, l_run = 0.f;  // live in wave 0

    // ---- A staging map: thread -> local row t>>3, chunk t&7 (4 floats) ----
    const int arow = t >> 3, ac = t & 7;
    const unsigned awr = (unsigned)(arow * 64 +
        ((((ac >> 1) ^ ((arow ^ (arow >> 2)) & 3)) << 4) | ((ac & 1) << 3)));

    // ---- A fragment read addresses ----
    unsigned ard[4];
#pragma unroll
    for (int mf = 0; mf < 4; ++mf) {
        int r = wm * 64 + mf * 16 + lr;
        ard[mf] = (unsigned)(r * 64 + ((g ^ ((r ^ (r >> 2)) & 3)) << 4));
    }

    for (int at = 0; at < 2; ++at) {
        const bool last = (at == 1);
        const int m0 = at * 128;

        const float* Ag = imgb + (size_t)min(m0 + arow, A_RG - 1) * DVD + ac * 4;

        f32x4 acc[4][4] = {};
        f32x4 rA;
        s16x8 aF[4], bR[4];

        auto ldA = [&](int kt) {
            rA = *(const f32x4*)(Ag + (size_t)kt * 32);
        };
        auto wrA = [&](int buf) {
            u32x2 pk;
            pk[0] = cvt2(rA[0], rA[1]);
            pk[1] = cvt2(rA[2], rA[3]);
            *(u32x2*)((char*)A_s[buf] + awr) = pk;
        };
        auto ldB = [&](int kt) {
            const char* p = Bp + (size_t)kt * 32768;
#pragma unroll
            for (int n = 0; n < 4; ++n)
                bR[n] = *(const s16x8*)(p + n * 1024);
        };

        // ---- prologue: B(0), A(0)->LDS buf0 ----
        ldB(0);
        ldA(0);
        wrA(0);
        asm volatile("s_waitcnt lgkmcnt(0)" ::: "memory");
        __builtin_amdgcn_sched_barrier(0);
        __builtin_amdgcn_s_barrier();

        // ---- K loop: 1 barrier/kstep (R16-proven) ----
        for (int kt = 0; kt < NKT; ++kt) {
            if (kt + 1 < NKT) ldA(kt + 1);           // HBM, lands by wrA below
            const char* Ac = (const char*)A_s[kt & 1];
#pragma unroll
            for (int mf = 0; mf < 4; ++mf)
                aF[mf] = *(const s16x8*)(Ac + ard[mf]);
            __builtin_amdgcn_s_setprio(1);
#pragma unroll
            for (int mf = 0; mf < 4; ++mf)
#pragma unroll
                for (int n = 0; n < 4; ++n)
                    acc[mf][n] = __builtin_amdgcn_mfma_f32_16x16x32_bf16(
                        aF[mf], bR[n], acc[mf][n], 0, 0, 0);
            __builtin_amdgcn_s_setprio(0);
            if (kt + 1 < NKT) {
                ldB(kt + 1);                         // WAR reload, L2/L1
                wrA((kt + 1) & 1);                   // waits rA (auto vmcnt)
                asm volatile("s_waitcnt lgkmcnt(0)" ::: "memory");
                __builtin_amdgcn_sched_barrier(0);
                __builtin_amdgcn_s_barrier();
            }
        }

        // ---- score epilogue: this wave's 64 cols -> att_part[wn][row] ----
        {
            float wfv[4], bs[4];
#pragma unroll
            for (int n = 0; n < 4; ++n) {
                int col = wn * 64 + n * 16 + lr;
                wfv[n] = W_f[col];
                bs[n] = base_g[(size_t)b * H_SZ + col];
            }
#pragma unroll
            for (int mf = 0; mf < 4; ++mf) {
                float pj[4] = {0.f, 0.f, 0.f, 0.f};
#pragma unroll
                for (int n = 0; n < 4; ++n) {
                    float a0 = fmaxf(acc[mf][n][0] + bs[n], 0.f);
                    float a1 = fmaxf(acc[mf][n][1] + bs[n], 0.f);
                    float a2 = fmaxf(acc[mf][n][2] + bs[n], 0.f);
                    float a3 = fmaxf(acc[mf][n][3] + bs[n], 0.f);
                    pj[0] = fmaf(a0, wfv[n], pj[0]);
                    pj[1] = fmaf(a1, wfv[n], pj[1]);
                    pj[2] = fmaf(a2, wfv[n], pj[2]);
                    pj[3] = fmaf(a3, wfv[n], pj[3]);
                }
#pragma unroll
                for (int j = 0; j < 4; ++j) {
                    float s = pj[j];
                    s += __shfl_xor(s, 1);
                    s += __shfl_xor(s, 2);
                    s += __shfl_xor(s, 4);
                    s += __shfl_xor(s, 8);   // 16 lr-lanes of this row
                    if (lr == 0)
                        att_part[wn][wm * 64 + mf * 16 + g * 4 + j] = s;
                }
            }
        }
        __builtin_amdgcn_s_barrier();

        // ---- wave 0: online-softmax state update ----
        if (w == 0) {
            int gr0 = m0 + lane, gr1 = m0 + lane + 64;
            float s0, s1;
            {
                float a = 0.f, c = 0.f;
#pragma unroll
                for (int q = 0; q < 8; ++q) {
                    a += att_part[q][lane];
                    c += att_part[q][lane + 64];
                }
                s0 = (gr0 < A_RG) ? a : -1e30f;
                s1 = (gr1 < A_RG) ? c : -1e30f;
            }
            float mx = fmaxf(s0, s1);
            for (int d = 1; d < 64; d <<= 1) mx = fmaxf(mx, __shfl_xor(mx, d));
            float m_new = fmaxf(m_run, mx);
            float r = __expf(m_run - m_new);
            float e0 = __expf(s0 - m_new);
            float e1 = __expf(s1 - m_new);
            float es = e0 + e1;
            for (int d = 1; d < 64; d <<= 1) es += __shfl_xor(es, d);
            l_run = l_run * r + es;
            m_run = m_new;
            e_s[lane] = e0;
            e_s[lane + 64] = e1;
            if (lane == 0) {
                scal_r = r;
                if (last) scal_l = l_run;
            }
        }
        __builtin_amdgcn_s_barrier();

        // ---- V phase: o = o*r + sum_a e[a] * imgs[b, m0+a, 2t..2t+1] ----
        {
            float r = scal_r;
            o0 *= r; o1 *= r;
            const float2* vb = (const float2*)imgb + t;
            const int AV = last ? (A_RG - 128) : 128;   // 68 or 128
#pragma unroll 4
            for (int a = 0; a < AV; ++a) {
                float e = e_s[a];
                float2 v = vb[(size_t)(m0 + a) * (DVD / 2)];
                o0 = fmaf(e, v.x, o0);
                o1 = fmaf(e, v.y, o1);
            }
        }
        // cross-tile LDS hazards covered by tile1's prologue fences
        // (R13/R16-verified pattern).
    }

    // ---- finalize: out[b, 2t..2t+1] = o / l ----
    float linv = 1.0f / scal_l;
    float2 res = make_float2(o0 * linv, o1 * linv);
    ((float2*)(out + (size_t)b * DVD))[t] = res;
}

// ---------------------------------------------------------------------------
extern "C" void kernel_launch(void* const* d_in, const int* in_sizes, int n_in,
                              void* d_out, int out_size, void* d_ws, size_t ws_size,
                              hipStream_t stream) {
    const float* h_att   = (const float*)d_in[0];
    const float* prev_h2 = (const float*)d_in[1];
    const float* imgs    = (const float*)d_in[2];
    const float* W_v     = (const float*)d_in[3];
    const float* b_v     = (const float*)d_in[4];
    const float* W_ha    = (const float*)d_in[5];
    const float* b_ha    = (const float*)d_in[6];
    const float* W_hv    = (const float*)d_in[7];
    const float* b_hv    = (const float*)d_in[8];
    const float* W_f     = (const float*)d_in[9];
    // d_in[10] = b_f: softmax-invariant additive constant -> unused

    // ws layout: [0,2MB) Wt4 bf16 fragment-packed; [2MB,+512KB) base fp32
    unsigned short* Wt4 = (unsigned short*)d_ws;
    float* base_g = (float*)((char*)d_ws + (size_t)DVD * H_SZ * 2);
    float* out = (float*)d_out;

    hipLaunchKernelGGL(k_prepW, dim3(256), dim3(256), 0, stream, W_v, Wt4);
    hipLaunchKernelGGL(k_base, dim3(4, B_SZ), dim3(256), 0, stream,
                       h_att, prev_h2, W_ha, b_ha, W_hv, b_hv, b_v, base_g);
    hipLaunchKernelGGL(k_fused, dim3(B_SZ), dim3(1024), 0, stream,
                       imgs, Wt4, base_g, W_f, out);
}